// Round 1
// baseline (143.009 us; speedup 1.0000x reference)
//
#include <hip/hip_runtime.h>
#include <math.h>

#define B_      16
#define H_      32
#define KVH_    8
#define G_      4
#define D_      128
#define BS_     16
#define L_      4096
#define MAXB_   256
#define T_      4096
#define NPART_  8
#define PART_   512
#define SCALE_  0.08838834764831843f

__device__ __forceinline__ int seq_len_of(int ctx) {
  return (ctx >= L_) ? (L_ - BS_ + (ctx & (BS_ - 1)) + 1) : (ctx + 1);
}

// Kernel 1: RoPE table, [T][64] pairs of (cos, sin) interleaved.
// Argument computed in f32 (matches reference semantics), transcendental in f64.
__global__ void rope_table_kernel(float* __restrict__ tab) {
  int idx = blockIdx.x * blockDim.x + threadIdx.x;
  if (idx >= T_ * 64) return;
  int t = idx >> 6, i = idx & 63;
  double inv = pow(10000.0, -(double)(2 * i) / 128.0);
  float ang = (float)t * (float)inv;   // f32 argument, like the reference
  double a = (double)ang;
  tab[2 * idx]     = (float)cos(a);
  tab[2 * idx + 1] = (float)sin(a);
}

// Kernel 2: partial attention per (b, kvh, partition).
// 256 threads = 4 waves; each wave: 4 groups of 16 lanes, one position per group.
// Lane dg holds dims [4dg..4dg+3] and [64+4dg..64+4dg+3] (4 RoPE pairs, local).
__global__ __launch_bounds__(256) void attn_partial_kernel(
    const float* __restrict__ q, const float* __restrict__ knew,
    const float* __restrict__ vnew, const float* __restrict__ kc,
    const float* __restrict__ vc, const int* __restrict__ btab,
    const int* __restrict__ ctxl, const float* __restrict__ tab,
    float* __restrict__ opart, float2* __restrict__ ml) {
  int bid  = blockIdx.x;
  int part = bid & (NPART_ - 1);
  int kvh  = (bid >> 3) & (KVH_ - 1);
  int b    = bid >> 6;

  int seq = seq_len_of(ctxl[b]);
  int t0 = part * PART_;
  if (t0 >= seq) return;                 // uniform per block: safe early exit
  int t1 = min(t0 + PART_, seq);
  int posq = seq - 1;

  int lane = threadIdx.x & 63;
  int wave = threadIdx.x >> 6;
  int tsub = lane >> 4;
  int dg   = lane & 15;

  const float4* tab4 = (const float4*)tab;
  float4 cq0 = tab4[posq * 32 + 2 * dg];
  float4 cq1 = tab4[posq * 32 + 2 * dg + 1];

  // roped + scaled q fragments for the 4 heads of this kv group
  float q1[G_][4], q2[G_][4];
#pragma unroll
  for (int g = 0; g < G_; ++g) {
    const float* qp = q + b * (H_ * D_) + (kvh * G_ + g) * D_;
    float4 a  = *(const float4*)(qp + 4 * dg);
    float4 bq = *(const float4*)(qp + 64 + 4 * dg);
    q1[g][0] = (a.x * cq0.x - bq.x * cq0.y) * SCALE_;
    q2[g][0] = (bq.x * cq0.x + a.x * cq0.y) * SCALE_;
    q1[g][1] = (a.y * cq0.z - bq.y * cq0.w) * SCALE_;
    q2[g][1] = (bq.y * cq0.z + a.y * cq0.w) * SCALE_;
    q1[g][2] = (a.z * cq1.x - bq.z * cq1.y) * SCALE_;
    q2[g][2] = (bq.z * cq1.x + a.z * cq1.y) * SCALE_;
    q1[g][3] = (a.w * cq1.z - bq.w * cq1.w) * SCALE_;
    q2[g][3] = (bq.w * cq1.z + a.w * cq1.w) * SCALE_;
  }

  // current-token k (roped at posq) and v fragments
  float kn1[4], kn2[4];
  float4 vna, vnb;
  {
    const float* kp = knew + b * (KVH_ * D_) + kvh * D_;
    float4 a  = *(const float4*)(kp + 4 * dg);
    float4 bq = *(const float4*)(kp + 64 + 4 * dg);
    kn1[0] = a.x * cq0.x - bq.x * cq0.y;  kn2[0] = bq.x * cq0.x + a.x * cq0.y;
    kn1[1] = a.y * cq0.z - bq.y * cq0.w;  kn2[1] = bq.y * cq0.z + a.y * cq0.w;
    kn1[2] = a.z * cq1.x - bq.z * cq1.y;  kn2[2] = bq.z * cq1.x + a.z * cq1.y;
    kn1[3] = a.w * cq1.z - bq.w * cq1.w;  kn2[3] = bq.w * cq1.z + a.w * cq1.w;
    const float* vp = vnew + b * (KVH_ * D_) + kvh * D_;
    vna = *(const float4*)(vp + 4 * dg);
    vnb = *(const float4*)(vp + 64 + 4 * dg);
  }

  float m[G_], l[G_], acc[G_][8];
#pragma unroll
  for (int g = 0; g < G_; ++g) {
    m[g] = -1e30f; l[g] = 0.f;
#pragma unroll
    for (int j = 0; j < 8; ++j) acc[g][j] = 0.f;
  }

  for (int tq = t0 + 4 * wave; tq < t1; tq += 16) {
    int t = tq + tsub;
    if (t < t1) {
      int blk  = btab[b * MAXB_ + (t >> 4)];
      int base = ((blk * BS_ + (t & (BS_ - 1))) * KVH_ + kvh) * D_;
      const float4* kc4 = (const float4*)(kc + base);
      const float4* vc4 = (const float4*)(vc + base);
      float4 ka = kc4[dg],      kb = kc4[16 + dg];
      float4 va = vc4[dg],      vb = vc4[16 + dg];
      float4 c0 = tab4[t * 32 + 2 * dg];
      float4 c1 = tab4[t * 32 + 2 * dg + 1];

      float kr1[4], kr2[4];
      kr1[0] = ka.x * c0.x - kb.x * c0.y;  kr2[0] = kb.x * c0.x + ka.x * c0.y;
      kr1[1] = ka.y * c0.z - kb.y * c0.w;  kr2[1] = kb.y * c0.z + ka.y * c0.w;
      kr1[2] = ka.z * c1.x - kb.z * c1.y;  kr2[2] = kb.z * c1.x + ka.z * c1.y;
      kr1[3] = ka.w * c1.z - kb.w * c1.w;  kr2[3] = kb.w * c1.z + ka.w * c1.w;
      if (t == posq) {                     // uniform within a 16-lane group
#pragma unroll
        for (int j = 0; j < 4; ++j) { kr1[j] = kn1[j]; kr2[j] = kn2[j]; }
        va = vna; vb = vnb;
      }

      float s[G_];
#pragma unroll
      for (int g = 0; g < G_; ++g) {
        s[g] = kr1[0] * q1[g][0] + kr2[0] * q2[g][0]
             + kr1[1] * q1[g][1] + kr2[1] * q2[g][1]
             + kr1[2] * q1[g][2] + kr2[2] * q2[g][2]
             + kr1[3] * q1[g][3] + kr2[3] * q2[g][3];
      }
#pragma unroll
      for (int off = 1; off <= 8; off <<= 1) {
#pragma unroll
        for (int g = 0; g < G_; ++g) s[g] += __shfl_xor(s[g], off);
      }
#pragma unroll
      for (int g = 0; g < G_; ++g) {
        float sv = s[g];
        float p;
        if (sv > m[g]) {
          float corr = __expf(m[g] - sv);
          l[g] *= corr;
#pragma unroll
          for (int j = 0; j < 8; ++j) acc[g][j] *= corr;
          m[g] = sv;
          p = 1.0f;
        } else {
          p = __expf(sv - m[g]);
        }
        l[g] += p;
        acc[g][0] += p * va.x; acc[g][1] += p * va.y;
        acc[g][2] += p * va.z; acc[g][3] += p * va.w;
        acc[g][4] += p * vb.x; acc[g][5] += p * vb.y;
        acc[g][6] += p * vb.z; acc[g][7] += p * vb.w;
      }
    }
  }

  // online-softmax state merge across lane groups (xor 16, 32), then waves via LDS
  auto merge_off = [&](int off) {
#pragma unroll
    for (int g = 0; g < G_; ++g) {
      float mo = __shfl_xor(m[g], off);
      float lo = __shfl_xor(l[g], off);
      float M  = fmaxf(m[g], mo);
      float fa = __expf(m[g] - M);
      float fb = __expf(mo - M);
      l[g] = l[g] * fa + lo * fb;
      m[g] = M;
#pragma unroll
      for (int j = 0; j < 8; ++j) {
        float ao = __shfl_xor(acc[g][j], off);
        acc[g][j] = acc[g][j] * fa + ao * fb;
      }
    }
  };
  merge_off(16);
  merge_off(32);

  __shared__ float  lds_acc[4][G_][D_];
  __shared__ float2 lds_ml[4][G_];
  if (lane < 16) {
#pragma unroll
    for (int g = 0; g < G_; ++g) {
#pragma unroll
      for (int j = 0; j < 8; ++j) {
        int dim = (j < 4) ? (4 * dg + j) : (64 + 4 * dg + (j - 4));
        lds_acc[wave][g][dim] = acc[g][j];
      }
      if (lane == 0) lds_ml[wave][g] = make_float2(m[g], l[g]);
    }
  }
  __syncthreads();
  if (wave == 0) {
    int w = tsub;
#pragma unroll
    for (int g = 0; g < G_; ++g) {
      float2 t2 = lds_ml[w][g];
      m[g] = t2.x; l[g] = t2.y;
#pragma unroll
      for (int j = 0; j < 8; ++j) {
        int dim = (j < 4) ? (4 * dg + j) : (64 + 4 * dg + (j - 4));
        acc[g][j] = lds_acc[w][g][dim];
      }
    }
    merge_off(16);
    merge_off(32);
    if (lane < 16) {
#pragma unroll
      for (int g = 0; g < G_; ++g) {
        float* op = opart + (size_t)(bid * G_ + g) * D_;
#pragma unroll
        for (int j = 0; j < 8; ++j) {
          int dim = (j < 4) ? (4 * dg + j) : (64 + 4 * dg + (j - 4));
          op[dim] = acc[g][j];
        }
        if (lane == 0) ml[bid * G_ + g] = make_float2(m[g], l[g]);
      }
    }
  }
}

// Kernel 3: merge partitions, normalize, write output.
__global__ void attn_reduce_kernel(const float* __restrict__ opart,
                                   const float2* __restrict__ ml,
                                   const int* __restrict__ ctxl,
                                   float* __restrict__ out) {
  int bh = blockIdx.x;              // 0..B*H-1
  int b = bh >> 5, h = bh & 31;
  int kvh = h >> 2, g = h & 3;
  int d = threadIdx.x;              // 0..127
  int seq = seq_len_of(ctxl[b]);
  int nlive = (seq + PART_ - 1) >> 9;
  int base = (b * KVH_ + kvh) * NPART_;

  float M = -1e30f;
  for (int p = 0; p < nlive; ++p) M = fmaxf(M, ml[(base + p) * G_ + g].x);
  float L = 0.f, O = 0.f;
  for (int p = 0; p < nlive; ++p) {
    float2 mlv = ml[(base + p) * G_ + g];
    float f = __expf(mlv.x - M);
    L += mlv.y * f;
    O += opart[(size_t)((base + p) * G_ + g) * D_ + d] * f;
  }
  out[b * (H_ * D_) + h * D_ + d] = O / L;
}

extern "C" void kernel_launch(void* const* d_in, const int* in_sizes, int n_in,
                              void* d_out, int out_size, void* d_ws, size_t ws_size,
                              hipStream_t stream) {
  const float* q    = (const float*)d_in[0];
  const float* k    = (const float*)d_in[1];
  const float* v    = (const float*)d_in[2];
  const float* kc   = (const float*)d_in[3];
  const float* vc   = (const float*)d_in[4];
  const int*   btab = (const int*)d_in[5];
  const int*   ctxl = (const int*)d_in[6];
  float* out = (float*)d_out;

  float*  tab   = (float*)d_ws;                                  // 2 MB
  float*  opart = tab + (size_t)T_ * 64 * 2;                     // 2 MB
  float2* ml    = (float2*)(opart + (size_t)B_ * KVH_ * NPART_ * G_ * D_); // 32 KB

  rope_table_kernel<<<(T_ * 64 + 255) / 256, 256, 0, stream>>>(tab);
  attn_partial_kernel<<<B_ * KVH_ * NPART_, 256, 0, stream>>>(
      q, k, v, kc, vc, btab, ctxl, tab, opart, ml);
  attn_reduce_kernel<<<B_ * H_, D_, 0, stream>>>(opart, ml, ctxl, out);
}

// Round 2
// 119.323 us; speedup vs baseline: 1.1985x; 1.1985x over previous
//
#include <hip/hip_runtime.h>
#include <math.h>

#define B_      16
#define H_      32
#define KVH_    8
#define G_      4
#define D_      128
#define BS_     16
#define L_      4096
#define MAXB_   256
#define T_      4096
#define NPART_  16
#define PART_   256
#define SCALE_  0.08838834764831843f

__device__ __forceinline__ int seq_len_of(int ctx) {
  return (ctx >= L_) ? (L_ - BS_ + (ctx & (BS_ - 1)) + 1) : (ctx + 1);
}

// Kernel 1: RoPE table, [T][64] pairs of (cos, sin) interleaved.
// Argument computed in f32 (matches reference semantics), transcendental in f64.
__global__ void rope_table_kernel(float* __restrict__ tab) {
  int idx = blockIdx.x * blockDim.x + threadIdx.x;
  if (idx >= T_ * 64) return;
  int t = idx >> 6, i = idx & 63;
  double inv = pow(10000.0, -(double)(2 * i) / 128.0);
  float ang = (float)t * (float)inv;   // f32 argument, like the reference
  double a = (double)ang;
  tab[2 * idx]     = (float)cos(a);
  tab[2 * idx + 1] = (float)sin(a);
}

// Kernel 2: partial attention per (b, kvh, partition).
// 256 threads = 4 waves; 16 lanes per position (4 positions/wave/iter).
// Lane dg holds dims [4dg..4dg+3] and [64+4dg..64+4dg+3] (4 RoPE pairs, local).
// Software-pipelined: named A/B register buffers, block table hoisted to LDS.

#define LOADK(P, tt)                                                        \
  {                                                                         \
    int blk_  = sblk[((tt) - t0) >> 4];                                     \
    int base_ = ((blk_ * BS_ + ((tt) & (BS_ - 1))) * KVH_ + kvh) * D_;      \
    const float4* kc4_ = (const float4*)(kc + base_);                       \
    const float4* vc4_ = (const float4*)(vc + base_);                       \
    P##ka = kc4_[dg];      P##kb = kc4_[16 + dg];                           \
    P##va = vc4_[dg];      P##vb = vc4_[16 + dg];                           \
    P##c0 = tab4[(tt) * 32 + 2 * dg];                                       \
    P##c1 = tab4[(tt) * 32 + 2 * dg + 1];                                   \
  }

#define COMPUTE(P, tt)                                                      \
  {                                                                         \
    float kr1[4], kr2[4];                                                   \
    kr1[0] = P##ka.x * P##c0.x - P##kb.x * P##c0.y;                         \
    kr2[0] = P##kb.x * P##c0.x + P##ka.x * P##c0.y;                         \
    kr1[1] = P##ka.y * P##c0.z - P##kb.y * P##c0.w;                         \
    kr2[1] = P##kb.y * P##c0.z + P##ka.y * P##c0.w;                         \
    kr1[2] = P##ka.z * P##c1.x - P##kb.z * P##c1.y;                         \
    kr2[2] = P##kb.z * P##c1.x + P##ka.z * P##c1.y;                         \
    kr1[3] = P##ka.w * P##c1.z - P##kb.w * P##c1.w;                         \
    kr2[3] = P##kb.w * P##c1.z + P##ka.w * P##c1.w;                         \
    float4 va_ = P##va, vb_ = P##vb;                                        \
    if ((tt) == posq) { /* cold, group-uniform: current-token k/v */        \
      const float* kp_ = knew + b * (KVH_ * D_) + kvh * D_;                 \
      float4 a_  = *(const float4*)(kp_ + 4 * dg);                          \
      float4 b_  = *(const float4*)(kp_ + 64 + 4 * dg);                     \
      float4 q0_ = tab4[posq * 32 + 2 * dg];                                \
      float4 q1_ = tab4[posq * 32 + 2 * dg + 1];                            \
      kr1[0] = a_.x * q0_.x - b_.x * q0_.y;                                 \
      kr2[0] = b_.x * q0_.x + a_.x * q0_.y;                                 \
      kr1[1] = a_.y * q0_.z - b_.y * q0_.w;                                 \
      kr2[1] = b_.y * q0_.z + a_.y * q0_.w;                                 \
      kr1[2] = a_.z * q1_.x - b_.z * q1_.y;                                 \
      kr2[2] = b_.z * q1_.x + a_.z * q1_.y;                                 \
      kr1[3] = a_.w * q1_.z - b_.w * q1_.w;                                 \
      kr2[3] = b_.w * q1_.z + a_.w * q1_.w;                                 \
      const float* vp_ = vnew + b * (KVH_ * D_) + kvh * D_;                 \
      va_ = *(const float4*)(vp_ + 4 * dg);                                 \
      vb_ = *(const float4*)(vp_ + 64 + 4 * dg);                            \
    }                                                                       \
    float s[G_];                                                            \
    _Pragma("unroll")                                                       \
    for (int g = 0; g < G_; ++g) {                                          \
      s[g] = kr1[0] * q1[g][0] + kr2[0] * q2[g][0]                          \
           + kr1[1] * q1[g][1] + kr2[1] * q2[g][1]                          \
           + kr1[2] * q1[g][2] + kr2[2] * q2[g][2]                          \
           + kr1[3] * q1[g][3] + kr2[3] * q2[g][3];                         \
    }                                                                       \
    _Pragma("unroll")                                                       \
    for (int off = 1; off <= 8; off <<= 1) {                                \
      _Pragma("unroll")                                                     \
      for (int g = 0; g < G_; ++g) s[g] += __shfl_xor(s[g], off);           \
    }                                                                       \
    _Pragma("unroll")                                                       \
    for (int g = 0; g < G_; ++g) {                                          \
      float sv = s[g];                                                      \
      float p;                                                              \
      if (sv > m[g]) {                                                      \
        float corr = __expf(m[g] - sv);                                     \
        l[g] *= corr;                                                       \
        _Pragma("unroll")                                                   \
        for (int j = 0; j < 8; ++j) acc[g][j] *= corr;                      \
        m[g] = sv;                                                          \
        p = 1.0f;                                                           \
      } else {                                                              \
        p = __expf(sv - m[g]);                                              \
      }                                                                     \
      l[g] += p;                                                            \
      acc[g][0] += p * va_.x; acc[g][1] += p * va_.y;                       \
      acc[g][2] += p * va_.z; acc[g][3] += p * va_.w;                       \
      acc[g][4] += p * vb_.x; acc[g][5] += p * vb_.y;                       \
      acc[g][6] += p * vb_.z; acc[g][7] += p * vb_.w;                       \
    }                                                                       \
  }

__global__ __launch_bounds__(256) void attn_partial_kernel(
    const float* __restrict__ q, const float* __restrict__ knew,
    const float* __restrict__ vnew, const float* __restrict__ kc,
    const float* __restrict__ vc, const int* __restrict__ btab,
    const int* __restrict__ ctxl, const float* __restrict__ tab,
    float* __restrict__ opart, float2* __restrict__ ml) {
  int bid  = blockIdx.x;
  int part = bid & (NPART_ - 1);
  int kvh  = (bid >> 4) & (KVH_ - 1);
  int b    = bid >> 7;

  int seq = seq_len_of(ctxl[b]);
  int t0 = part * PART_;
  if (t0 >= seq) return;                 // uniform per block: safe early exit
  int t1 = min(t0 + PART_, seq);
  int posq = seq - 1;

  int lane = threadIdx.x & 63;
  int wave = threadIdx.x >> 6;
  int tsub = lane >> 4;
  int dg   = lane & 15;

  // block table slice for this partition -> LDS (index == (t - t0) >> 4)
  __shared__ int sblk[PART_ / BS_];
  if (threadIdx.x < PART_ / BS_)
    sblk[threadIdx.x] = btab[b * MAXB_ + (t0 >> 4) + threadIdx.x];
  __syncthreads();

  const float4* tab4 = (const float4*)tab;

  // roped + scaled q fragments for the 4 heads of this kv group
  float q1[G_][4], q2[G_][4];
  {
    float4 cq0 = tab4[posq * 32 + 2 * dg];
    float4 cq1 = tab4[posq * 32 + 2 * dg + 1];
#pragma unroll
    for (int g = 0; g < G_; ++g) {
      const float* qp = q + b * (H_ * D_) + (kvh * G_ + g) * D_;
      float4 a  = *(const float4*)(qp + 4 * dg);
      float4 bq = *(const float4*)(qp + 64 + 4 * dg);
      q1[g][0] = (a.x * cq0.x - bq.x * cq0.y) * SCALE_;
      q2[g][0] = (bq.x * cq0.x + a.x * cq0.y) * SCALE_;
      q1[g][1] = (a.y * cq0.z - bq.y * cq0.w) * SCALE_;
      q2[g][1] = (bq.y * cq0.z + a.y * cq0.w) * SCALE_;
      q1[g][2] = (a.z * cq1.x - bq.z * cq1.y) * SCALE_;
      q2[g][2] = (bq.z * cq1.x + a.z * cq1.y) * SCALE_;
      q1[g][3] = (a.w * cq1.z - bq.w * cq1.w) * SCALE_;
      q2[g][3] = (bq.w * cq1.z + a.w * cq1.w) * SCALE_;
    }
  }

  float m[G_], l[G_], acc[G_][8];
#pragma unroll
  for (int g = 0; g < G_; ++g) {
    m[g] = -1e30f; l[g] = 0.f;
#pragma unroll
    for (int j = 0; j < 8; ++j) acc[g][j] = 0.f;
  }

  // software-pipelined main loop (named A/B buffers, 1-deep prefetch)
  {
    float4 Aka, Akb, Ava, Avb, Ac0, Ac1;
    float4 Bka, Bkb, Bva, Bvb, Bc0, Bc1;
    int t = t0 + 4 * wave + tsub;        // group-uniform; shuffles stay in-group
    if (t < t1) {
      LOADK(A, t);
      while (1) {
        int t2 = t + 16;
        if (t2 < t1) LOADK(B, t2);
        COMPUTE(A, t);
        t = t2;
        if (t >= t1) break;
        t2 = t + 16;
        if (t2 < t1) LOADK(A, t2);
        COMPUTE(B, t);
        t = t2;
        if (t >= t1) break;
      }
    }
  }

  // online-softmax state merge across lane groups (xor 16, 32), then waves via LDS
  auto merge_off = [&](int off) {
#pragma unroll
    for (int g = 0; g < G_; ++g) {
      float mo = __shfl_xor(m[g], off);
      float lo = __shfl_xor(l[g], off);
      float M  = fmaxf(m[g], mo);
      float fa = __expf(m[g] - M);
      float fb = __expf(mo - M);
      l[g] = l[g] * fa + lo * fb;
      m[g] = M;
#pragma unroll
      for (int j = 0; j < 8; ++j) {
        float ao = __shfl_xor(acc[g][j], off);
        acc[g][j] = acc[g][j] * fa + ao * fb;
      }
    }
  };
  merge_off(16);
  merge_off(32);

  __shared__ float  lds_acc[4][G_][D_];
  __shared__ float2 lds_ml[4][G_];
  if (lane < 16) {
#pragma unroll
    for (int g = 0; g < G_; ++g) {
#pragma unroll
      for (int j = 0; j < 8; ++j) {
        int dim = (j < 4) ? (4 * dg + j) : (64 + 4 * dg + (j - 4));
        lds_acc[wave][g][dim] = acc[g][j];
      }
      if (lane == 0) lds_ml[wave][g] = make_float2(m[g], l[g]);
    }
  }
  __syncthreads();
  if (wave == 0) {
    int w = tsub;
#pragma unroll
    for (int g = 0; g < G_; ++g) {
      float2 t2 = lds_ml[w][g];
      m[g] = t2.x; l[g] = t2.y;
#pragma unroll
      for (int j = 0; j < 8; ++j) {
        int dim = (j < 4) ? (4 * dg + j) : (64 + 4 * dg + (j - 4));
        acc[g][j] = lds_acc[w][g][dim];
      }
    }
    merge_off(16);
    merge_off(32);
    if (lane < 16) {
#pragma unroll
      for (int g = 0; g < G_; ++g) {
        float* op = opart + (size_t)(bid * G_ + g) * D_;
#pragma unroll
        for (int j = 0; j < 8; ++j) {
          int dim = (j < 4) ? (4 * dg + j) : (64 + 4 * dg + (j - 4));
          op[dim] = acc[g][j];
        }
        if (lane == 0) ml[bid * G_ + g] = make_float2(m[g], l[g]);
      }
    }
  }
}

// Kernel 3: merge partitions, normalize, write output.
__global__ void attn_reduce_kernel(const float* __restrict__ opart,
                                   const float2* __restrict__ ml,
                                   const int* __restrict__ ctxl,
                                   float* __restrict__ out) {
  int bh = blockIdx.x;              // 0..B*H-1
  int b = bh >> 5, h = bh & 31;
  int kvh = h >> 2, g = h & 3;
  int d = threadIdx.x;              // 0..127
  int seq = seq_len_of(ctxl[b]);
  int nlive = (seq + PART_ - 1) / PART_;
  int base = (b * KVH_ + kvh) * NPART_;

  float M = -1e30f;
  for (int p = 0; p < nlive; ++p) M = fmaxf(M, ml[(base + p) * G_ + g].x);
  float L = 0.f, O = 0.f;
  for (int p = 0; p < nlive; ++p) {
    float2 mlv = ml[(base + p) * G_ + g];
    float f = __expf(mlv.x - M);
    L += mlv.y * f;
    O += opart[(size_t)((base + p) * G_ + g) * D_ + d] * f;
  }
  out[b * (H_ * D_) + h * D_ + d] = O / L;
}

extern "C" void kernel_launch(void* const* d_in, const int* in_sizes, int n_in,
                              void* d_out, int out_size, void* d_ws, size_t ws_size,
                              hipStream_t stream) {
  const float* q    = (const float*)d_in[0];
  const float* k    = (const float*)d_in[1];
  const float* v    = (const float*)d_in[2];
  const float* kc   = (const float*)d_in[3];
  const float* vc   = (const float*)d_in[4];
  const int*   btab = (const int*)d_in[5];
  const int*   ctxl = (const int*)d_in[6];
  float* out = (float*)d_out;

  float*  tab   = (float*)d_ws;                                  // 2 MB
  float*  opart = tab + (size_t)T_ * 64 * 2;                     // 4 MB
  float2* ml    = (float2*)(opart + (size_t)B_ * KVH_ * NPART_ * G_ * D_); // 64 KB

  rope_table_kernel<<<(T_ * 64 + 255) / 256, 256, 0, stream>>>(tab);
  attn_partial_kernel<<<B_ * KVH_ * NPART_, 256, 0, stream>>>(
      q, k, v, kc, vc, btab, ctxl, tab, opart, ml);
  attn_reduce_kernel<<<B_ * H_, D_, 0, stream>>>(opart, ml, ctxl, out);
}

// Round 3
// 119.066 us; speedup vs baseline: 1.2011x; 1.0022x over previous
//
#include <hip/hip_runtime.h>
#include <math.h>

#define B_      16
#define H_      32
#define KVH_    8
#define G_      4
#define D_      128
#define BS_     16
#define L_      4096
#define MAXB_   256
#define T_      4096
#define NPART_  16
#define PART_   256
#define SCALE_  0.08838834764831843f

__device__ __forceinline__ int seq_len_of(int ctx) {
  return (ctx >= L_) ? (L_ - BS_ + (ctx & (BS_ - 1)) + 1) : (ctx + 1);
}

// Kernel 1: RoPE table, [T][64] pairs of (cos, sin) interleaved.
// Argument computed in f32 (matches reference semantics), transcendental in f64.
__global__ void rope_table_kernel(float* __restrict__ tab) {
  int idx = blockIdx.x * blockDim.x + threadIdx.x;
  if (idx >= T_ * 64) return;
  int t = idx >> 6, i = idx & 63;
  double inv = pow(10000.0, -(double)(2 * i) / 128.0);
  float ang = (float)t * (float)inv;   // f32 argument, like the reference
  double a = (double)ang;
  tab[2 * idx]     = (float)cos(a);
  tab[2 * idx + 1] = (float)sin(a);
}

// Kernel 2: partial attention per (b, kvh, partition).
// 256 threads = 4 waves; 16 lanes per position (4 positions/wave/iter).
// Lane dg holds dims [4dg..4dg+3] and [64+4dg..64+4dg+3] (4 RoPE pairs, local).
// Depth-2 software pipeline (A/B/C named buffers, K/V only); cos/sin advanced
// in-register via angle-addition (rotation by 16*theta per iteration).

#define LOADK(P, tt)                                                        \
  {                                                                         \
    int blk_  = sblk[((tt) - t0) >> 4];                                     \
    int base_ = ((blk_ * BS_ + ((tt) & (BS_ - 1))) * KVH_ + kvh) * D_;      \
    const float4* kc4_ = (const float4*)(kc + base_);                       \
    const float4* vc4_ = (const float4*)(vc + base_);                       \
    P##ka = kc4_[dg];      P##kb = kc4_[16 + dg];                           \
    P##va = vc4_[dg];      P##vb = vc4_[16 + dg];                           \
  }

#define COMPUTE(P, tt)                                                      \
  {                                                                         \
    float kr1[4], kr2[4];                                                   \
    kr1[0] = P##ka.x * cc0.x - P##kb.x * cc0.y;                             \
    kr2[0] = P##kb.x * cc0.x + P##ka.x * cc0.y;                             \
    kr1[1] = P##ka.y * cc0.z - P##kb.y * cc0.w;                             \
    kr2[1] = P##kb.y * cc0.z + P##ka.y * cc0.w;                             \
    kr1[2] = P##ka.z * cc1.x - P##kb.z * cc1.y;                             \
    kr2[2] = P##kb.z * cc1.x + P##ka.z * cc1.y;                             \
    kr1[3] = P##ka.w * cc1.z - P##kb.w * cc1.w;                             \
    kr2[3] = P##kb.w * cc1.z + P##ka.w * cc1.w;                             \
    float4 va_ = P##va, vb_ = P##vb;                                        \
    if ((tt) == posq) { /* cold, group-uniform: current-token k/v */        \
      const float* kp_ = knew + b * (KVH_ * D_) + kvh * D_;                 \
      float4 xa_ = *(const float4*)(kp_ + 4 * dg);                          \
      float4 xb_ = *(const float4*)(kp_ + 64 + 4 * dg);                     \
      float4 p0_ = tab4[posq * 32 + 2 * dg];                                \
      float4 p1_ = tab4[posq * 32 + 2 * dg + 1];                            \
      kr1[0] = xa_.x * p0_.x - xb_.x * p0_.y;                               \
      kr2[0] = xb_.x * p0_.x + xa_.x * p0_.y;                               \
      kr1[1] = xa_.y * p0_.z - xb_.y * p0_.w;                               \
      kr2[1] = xb_.y * p0_.z + xa_.y * p0_.w;                               \
      kr1[2] = xa_.z * p1_.x - xb_.z * p1_.y;                               \
      kr2[2] = xb_.z * p1_.x + xa_.z * p1_.y;                               \
      kr1[3] = xa_.w * p1_.z - xb_.w * p1_.w;                               \
      kr2[3] = xb_.w * p1_.z + xa_.w * p1_.w;                               \
      const float* vp_ = vnew + b * (KVH_ * D_) + kvh * D_;                 \
      va_ = *(const float4*)(vp_ + 4 * dg);                                 \
      vb_ = *(const float4*)(vp_ + 64 + 4 * dg);                            \
    }                                                                       \
    float s[G_];                                                            \
    _Pragma("unroll")                                                       \
    for (int g = 0; g < G_; ++g) {                                          \
      s[g] = kr1[0] * q1[g][0] + kr2[0] * q2[g][0]                          \
           + kr1[1] * q1[g][1] + kr2[1] * q2[g][1]                          \
           + kr1[2] * q1[g][2] + kr2[2] * q2[g][2]                          \
           + kr1[3] * q1[g][3] + kr2[3] * q2[g][3];                         \
    }                                                                       \
    _Pragma("unroll")                                                       \
    for (int off = 1; off <= 8; off <<= 1) {                                \
      _Pragma("unroll")                                                     \
      for (int g = 0; g < G_; ++g) s[g] += __shfl_xor(s[g], off);           \
    }                                                                       \
    _Pragma("unroll")                                                       \
    for (int g = 0; g < G_; ++g) {                                          \
      float sv   = s[g];                                                    \
      float mn   = fmaxf(m[g], sv);                                         \
      float corr = __expf(m[g] - mn);                                       \
      float p    = __expf(sv - mn);                                         \
      m[g] = mn;                                                            \
      l[g] = l[g] * corr + p;                                               \
      acc[g][0] = acc[g][0] * corr + p * va_.x;                             \
      acc[g][1] = acc[g][1] * corr + p * va_.y;                             \
      acc[g][2] = acc[g][2] * corr + p * va_.z;                             \
      acc[g][3] = acc[g][3] * corr + p * va_.w;                             \
      acc[g][4] = acc[g][4] * corr + p * vb_.x;                             \
      acc[g][5] = acc[g][5] * corr + p * vb_.y;                             \
      acc[g][6] = acc[g][6] * corr + p * vb_.z;                             \
      acc[g][7] = acc[g][7] * corr + p * vb_.w;                             \
    }                                                                       \
    { /* advance cos/sin by 16*theta (angle addition) */                    \
      float nc_;                                                            \
      nc_ = cc0.x * r0.x - cc0.y * r0.y;                                    \
      cc0.y = cc0.y * r0.x + cc0.x * r0.y; cc0.x = nc_;                     \
      nc_ = cc0.z * r0.z - cc0.w * r0.w;                                    \
      cc0.w = cc0.w * r0.z + cc0.z * r0.w; cc0.z = nc_;                     \
      nc_ = cc1.x * r1.x - cc1.y * r1.y;                                    \
      cc1.y = cc1.y * r1.x + cc1.x * r1.y; cc1.x = nc_;                     \
      nc_ = cc1.z * r1.z - cc1.w * r1.w;                                    \
      cc1.w = cc1.w * r1.z + cc1.z * r1.w; cc1.z = nc_;                     \
    }                                                                       \
  }

__global__ __launch_bounds__(256) void attn_partial_kernel(
    const float* __restrict__ q, const float* __restrict__ knew,
    const float* __restrict__ vnew, const float* __restrict__ kc,
    const float* __restrict__ vc, const int* __restrict__ btab,
    const int* __restrict__ ctxl, const float* __restrict__ tab,
    float* __restrict__ opart, float2* __restrict__ ml) {
  int bid  = blockIdx.x;
  int part = bid & (NPART_ - 1);
  int kvh  = (bid >> 4) & (KVH_ - 1);
  int b    = bid >> 7;

  int seq = seq_len_of(ctxl[b]);
  int t0 = part * PART_;
  if (t0 >= seq) return;                 // uniform per block: safe early exit
  int t1 = min(t0 + PART_, seq);
  int posq = seq - 1;

  int lane = threadIdx.x & 63;
  int wave = threadIdx.x >> 6;
  int tsub = lane >> 4;
  int dg   = lane & 15;

  // block table slice for this partition -> LDS (index == (t - t0) >> 4)
  __shared__ int sblk[PART_ / BS_];
  if (threadIdx.x < PART_ / BS_)
    sblk[threadIdx.x] = btab[b * MAXB_ + (t0 >> 4) + threadIdx.x];
  __syncthreads();

  const float4* tab4 = (const float4*)tab;

  // per-lane cos/sin state at t_start, and rotation constants (row 16)
  int tstart = t0 + 4 * wave + tsub;
  float4 cc0 = tab4[tstart * 32 + 2 * dg];
  float4 cc1 = tab4[tstart * 32 + 2 * dg + 1];
  float4 r0  = tab4[16 * 32 + 2 * dg];
  float4 r1  = tab4[16 * 32 + 2 * dg + 1];

  // roped + scaled q fragments for the 4 heads of this kv group
  float q1[G_][4], q2[G_][4];
  {
    float4 cq0 = tab4[posq * 32 + 2 * dg];
    float4 cq1 = tab4[posq * 32 + 2 * dg + 1];
#pragma unroll
    for (int g = 0; g < G_; ++g) {
      const float* qp = q + b * (H_ * D_) + (kvh * G_ + g) * D_;
      float4 a  = *(const float4*)(qp + 4 * dg);
      float4 bq = *(const float4*)(qp + 64 + 4 * dg);
      q1[g][0] = (a.x * cq0.x - bq.x * cq0.y) * SCALE_;
      q2[g][0] = (bq.x * cq0.x + a.x * cq0.y) * SCALE_;
      q1[g][1] = (a.y * cq0.z - bq.y * cq0.w) * SCALE_;
      q2[g][1] = (bq.y * cq0.z + a.y * cq0.w) * SCALE_;
      q1[g][2] = (a.z * cq1.x - bq.z * cq1.y) * SCALE_;
      q2[g][2] = (bq.z * cq1.x + a.z * cq1.y) * SCALE_;
      q1[g][3] = (a.w * cq1.z - bq.w * cq1.w) * SCALE_;
      q2[g][3] = (bq.w * cq1.z + a.w * cq1.w) * SCALE_;
    }
  }

  float m[G_], l[G_], acc[G_][8];
#pragma unroll
  for (int g = 0; g < G_; ++g) {
    m[g] = -1e30f; l[g] = 0.f;
#pragma unroll
    for (int j = 0; j < 8; ++j) acc[g][j] = 0.f;
  }

  // depth-2 software pipeline: compute(A) while B and C are in flight
  {
    float4 Aka, Akb, Ava, Avb;
    float4 Bka, Bkb, Bva, Bvb;
    float4 Cka, Ckb, Cva, Cvb;
    int t = t0 + 4 * wave + tsub;        // group-uniform; shuffles stay in-group
    if (t < t1) {
      LOADK(A, t);
      if (t + 16 < t1) LOADK(B, t + 16);
      while (1) {
        if (t + 32 < t1) LOADK(C, t + 32);
        COMPUTE(A, t);
        t += 16; if (t >= t1) break;
        if (t + 32 < t1) LOADK(A, t + 32);
        COMPUTE(B, t);
        t += 16; if (t >= t1) break;
        if (t + 32 < t1) LOADK(B, t + 32);
        COMPUTE(C, t);
        t += 16; if (t >= t1) break;
      }
    }
  }

  // online-softmax state merge across lane groups (xor 16, 32), then waves via LDS
  auto merge_off = [&](int off) {
#pragma unroll
    for (int g = 0; g < G_; ++g) {
      float mo = __shfl_xor(m[g], off);
      float lo = __shfl_xor(l[g], off);
      float M  = fmaxf(m[g], mo);
      float fa = __expf(m[g] - M);
      float fb = __expf(mo - M);
      l[g] = l[g] * fa + lo * fb;
      m[g] = M;
#pragma unroll
      for (int j = 0; j < 8; ++j) {
        float ao = __shfl_xor(acc[g][j], off);
        acc[g][j] = acc[g][j] * fa + ao * fb;
      }
    }
  };
  merge_off(16);
  merge_off(32);

  __shared__ float  lds_acc[4][G_][D_];
  __shared__ float2 lds_ml[4][G_];
  if (lane < 16) {
#pragma unroll
    for (int g = 0; g < G_; ++g) {
#pragma unroll
      for (int j = 0; j < 8; ++j) {
        int dim = (j < 4) ? (4 * dg + j) : (64 + 4 * dg + (j - 4));
        lds_acc[wave][g][dim] = acc[g][j];
      }
      if (lane == 0) lds_ml[wave][g] = make_float2(m[g], l[g]);
    }
  }
  __syncthreads();
  if (wave == 0) {
    int w = tsub;
#pragma unroll
    for (int g = 0; g < G_; ++g) {
      float2 t2 = lds_ml[w][g];
      m[g] = t2.x; l[g] = t2.y;
#pragma unroll
      for (int j = 0; j < 8; ++j) {
        int dim = (j < 4) ? (4 * dg + j) : (64 + 4 * dg + (j - 4));
        acc[g][j] = lds_acc[w][g][dim];
      }
    }
    merge_off(16);
    merge_off(32);
    if (lane < 16) {
#pragma unroll
      for (int g = 0; g < G_; ++g) {
        float* op = opart + (size_t)(bid * G_ + g) * D_;
#pragma unroll
        for (int j = 0; j < 8; ++j) {
          int dim = (j < 4) ? (4 * dg + j) : (64 + 4 * dg + (j - 4));
          op[dim] = acc[g][j];
        }
        if (lane == 0) ml[bid * G_ + g] = make_float2(m[g], l[g]);
      }
    }
  }
}

// Kernel 3: merge partitions, normalize, write output.
__global__ void attn_reduce_kernel(const float* __restrict__ opart,
                                   const float2* __restrict__ ml,
                                   const int* __restrict__ ctxl,
                                   float* __restrict__ out) {
  int bh = blockIdx.x;              // 0..B*H-1
  int b = bh >> 5, h = bh & 31;
  int kvh = h >> 2, g = h & 3;
  int d = threadIdx.x;              // 0..127
  int seq = seq_len_of(ctxl[b]);
  int nlive = (seq + PART_ - 1) / PART_;
  int base = (b * KVH_ + kvh) * NPART_;

  float M = -1e30f;
  for (int p = 0; p < nlive; ++p) M = fmaxf(M, ml[(base + p) * G_ + g].x);
  float L = 0.f, O = 0.f;
  for (int p = 0; p < nlive; ++p) {
    float2 mlv = ml[(base + p) * G_ + g];
    float f = __expf(mlv.x - M);
    L += mlv.y * f;
    O += opart[(size_t)((base + p) * G_ + g) * D_ + d] * f;
  }
  out[b * (H_ * D_) + h * D_ + d] = O / L;
}

extern "C" void kernel_launch(void* const* d_in, const int* in_sizes, int n_in,
                              void* d_out, int out_size, void* d_ws, size_t ws_size,
                              hipStream_t stream) {
  const float* q    = (const float*)d_in[0];
  const float* k    = (const float*)d_in[1];
  const float* v    = (const float*)d_in[2];
  const float* kc   = (const float*)d_in[3];
  const float* vc   = (const float*)d_in[4];
  const int*   btab = (const int*)d_in[5];
  const int*   ctxl = (const int*)d_in[6];
  float* out = (float*)d_out;

  float*  tab   = (float*)d_ws;                                  // 2 MB
  float*  opart = tab + (size_t)T_ * 64 * 2;                     // 4 MB
  float2* ml    = (float2*)(opart + (size_t)B_ * KVH_ * NPART_ * G_ * D_); // 64 KB

  rope_table_kernel<<<(T_ * 64 + 255) / 256, 256, 0, stream>>>(tab);
  attn_partial_kernel<<<B_ * KVH_ * NPART_, 256, 0, stream>>>(
      q, k, v, kc, vc, btab, ctxl, tab, opart, ml);
  attn_reduce_kernel<<<B_ * H_, D_, 0, stream>>>(opart, ml, ctxl, out);
}